// Round 1
// baseline (686.488 us; speedup 1.0000x reference)
//
#include <hip/hip_runtime.h>
#include <hip/hip_bf16.h>

// Hyperbolic GNN layer.
// D is fixed at 64 (= wavefront size): one wave handles one edge/node row.

__device__ __forceinline__ float wave_sum(float v) {
#pragma unroll
    for (int off = 32; off > 0; off >>= 1) v += __shfl_xor(v, off, 64);
    return v;
}

// expmap0 of a vector u is a pure scalar multiple of u:
//   s = tanh(min(un,15))/un * min(1, maxn/n_gamma),  un = max(||u||,1e-15)
// returns scale s; also outputs x2 = ||s*u||^2.
__device__ __forceinline__ void expmap0_scale(float norm, float& s, float& x2) {
    const float maxn = 1.0f - 0.004f;
    float un = fmaxf(norm, 1e-15f);
    float th = tanhf(fminf(un, 15.0f));
    float gs = th / un;
    float ng = gs * norm;                 // ||gamma||
    float ps = ng > maxn ? maxn / ng : 1.0f;
    s = gs * ps;
    float sn = s * norm;
    x2 = sn * sn;
}

// --- prep for rel tables (R waves) and query rows (B waves) ---
__global__ void prep_small_kernel(const int* __restrict__ q_rel,
                                  const float* __restrict__ query_embed,
                                  const float* __restrict__ Wqr_w,
                                  const float* __restrict__ Wqr_b,
                                  const float* __restrict__ rela_embed,
                                  const float* __restrict__ Wr,
                                  float* __restrict__ hr_h,    // [R][64]
                                  float* __restrict__ hr_aux,  // [R][8]: 0..A-1 hrw, 6 = y2
                                  float* __restrict__ preq,    // [B][8]: 0..A-1
                                  int R, int B, int A) {
    int w = (blockIdx.x * blockDim.x + threadIdx.x) >> 6;
    int lane = threadIdx.x & 63;
    if (w < R) {
        int r = w;
        float u = rela_embed[r * 64 + lane];
        float n2 = wave_sum(u * u);
        float s, y2;
        expmap0_scale(sqrtf(n2), s, y2);
        hr_h[r * 64 + lane] = s * u;
        for (int a = 0; a < A; ++a) {
            float p = wave_sum(u * Wr[a * 64 + lane]);
            if (lane == 0) hr_aux[r * 8 + a] = p;
        }
        if (lane == 0) hr_aux[r * 8 + 6] = y2;
    } else if (w < R + B) {
        int b = w - R;
        int qr = q_rel[b];
        float q = query_embed[qr * 64 + lane];
        for (int a = 0; a < A; ++a) {
            float p = wave_sum(q * Wqr_w[a * 64 + lane]);
            if (lane == 0) preq[b * 8 + a] = p + Wqr_b[a];
        }
    }
}

// --- per-node tables: hsw[A], x2, scale (N waves) ---
__global__ void prep_node_kernel(const float* __restrict__ hidden,
                                 const float* __restrict__ Ws,
                                 float* __restrict__ hs_aux,  // [N][8]: 0..A-1 hsw, 6 = x2, 7 = scale
                                 int N, int A) {
    int w = (blockIdx.x * blockDim.x + threadIdx.x) >> 6;
    if (w >= N) return;
    int lane = threadIdx.x & 63;
    float u = hidden[(long)w * 64 + lane];
    float n2 = wave_sum(u * u);
    float s, x2;
    expmap0_scale(sqrtf(n2), s, x2);
    for (int a = 0; a < A; ++a) {
        float p = wave_sum(u * Ws[a * 64 + lane]);
        if (lane == 0) hs_aux[w * 8 + a] = p;
    }
    if (lane == 0) {
        hs_aux[w * 8 + 6] = x2;
        hs_aux[w * 8 + 7] = s;
    }
}

// --- main edge kernel: one wave per edge ---
__global__ void edge_kernel(const int* __restrict__ edges,
                            const float* __restrict__ hidden,
                            const float* __restrict__ hr_h,
                            const float* __restrict__ hr_aux,
                            const float* __restrict__ hs_aux,
                            const float* __restrict__ preq,
                            const float* __restrict__ walpha_w,
                            const float* __restrict__ walpha_b,
                            float* __restrict__ agg,
                            int E, int A) {
    int w = (blockIdx.x * blockDim.x + threadIdx.x) >> 6;
    if (w >= E) return;
    int lane = threadIdx.x & 63;
    const int* er = edges + (long)w * 6;
    int r_idx = er[0];
    int rel   = er[2];
    int sub   = er[4];
    int obj   = er[5];

    float s  = hs_aux[(long)sub * 8 + 7];
    float x2 = hs_aux[(long)sub * 8 + 6];
    float x  = hidden[(long)sub * 64 + lane] * s;   // hs_h
    float y  = hr_h[rel * 64 + lane];               // hr_h
    float y2 = hr_aux[rel * 8 + 6];

    float xy = wave_sum(x * y);

    // alpha = sigmoid(relu(pre) . walpha_w + walpha_b)
    float zz = 0.f;
    for (int a = 0; a < A; ++a) {
        float pre = hs_aux[(long)sub * 8 + a] + hr_aux[rel * 8 + a] + preq[r_idx * 8 + a];
        zz += fmaxf(pre, 0.f) * walpha_w[a];
    }
    float alpha = 1.f / (1.f + expf(-(zz + walpha_b[0])));

    // mobius_add (c=1), analytic norm
    float Af = 1.f + 2.f * xy + y2;
    float Bf = 1.f - x2;
    float den = fmaxf(1.f + 2.f * xy + x2 * y2, 1e-15f);
    float inv = 1.f / den;
    float m = (Af * x + Bf * y) * inv;
    float nm2 = fmaxf((Af * Af * x2 + 2.f * Af * Bf * xy + Bf * Bf * y2) * inv * inv, 0.f);
    float nm = sqrtf(nm2);

    // project
    const float maxn = 1.0f - 0.004f;
    if (nm > maxn) {
        m *= maxn / nm;
        nm = maxn;
    }

    // logmap0
    float yn = fmaxf(nm, 1e-15f);
    float t = fminf(yn, 1.f - 1e-5f);
    float art = 0.5f * (log1pf(t) - log1pf(-t));
    float msg = m * (art / yn) * alpha;

    unsafeAtomicAdd(agg + (long)obj * 64 + lane, msg);
}

// --- final: a = agg @ Wh^T (in-place per row), then p_exp_map + logmap0 ---
__global__ void final_kernel(float* __restrict__ out,
                             const float* __restrict__ Wh,
                             int N) {
    __shared__ float WhT[64 * 64];   // WhT[k][d] = Wh[d][k]
    int t = threadIdx.x;
    for (int i = t; i < 64 * 64; i += blockDim.x) {
        int row = i >> 6, col = i & 63;
        WhT[col * 64 + row] = Wh[i];
    }
    __syncthreads();

    int lane = t & 63;
    int wl = t >> 6;
    int wpb = blockDim.x >> 6;
    int wg = blockIdx.x * wpb + wl;
    int wstride = gridDim.x * wpb;

    for (int n = wg; n < N; n += wstride) {
        float v = out[(long)n * 64 + lane];
        float a = 0.f;
#pragma unroll
        for (int k = 0; k < 64; ++k)
            a = fmaf(__shfl(v, k, 64), WhT[k * 64 + lane], a);

        float n2 = wave_sum(a * a);
        float na = sqrtf(n2);
        float nv = fmaxf(na, 1e-10f);
        float pn = tanhf(nv);
        float p = pn * a / nv;                   // p_exp_map
        float np = pn * (na / nv);               // ||p||
        float yn = fmaxf(np, 1e-15f);
        float tt = fminf(yn, 1.f - 1e-5f);
        float art = 0.5f * (log1pf(tt) - log1pf(-tt));
        out[(long)n * 64 + lane] = p * (art / yn);
    }
}

extern "C" void kernel_launch(void* const* d_in, const int* in_sizes, int n_in,
                              void* d_out, int out_size, void* d_ws, size_t ws_size,
                              hipStream_t stream) {
    const int*   q_rel       = (const int*)d_in[1];
    const float* hidden      = (const float*)d_in[2];
    const int*   edges       = (const int*)d_in[3];
    const float* rela_embed  = (const float*)d_in[6];
    const float* query_embed = (const float*)d_in[7];
    const float* Ws          = (const float*)d_in[8];
    const float* Wr          = (const float*)d_in[9];
    const float* Wqr_w       = (const float*)d_in[10];
    const float* Wqr_b       = (const float*)d_in[11];
    const float* walpha_w    = (const float*)d_in[12];
    const float* walpha_b    = (const float*)d_in[13];
    const float* Wh          = (const float*)d_in[14];

    const int D = 64;
    int B = in_sizes[0];
    int E = in_sizes[3] / 6;
    int A = in_sizes[11];
    int R = in_sizes[6] / D;
    int N = out_size / D;

    float* out = (float*)d_out;

    // workspace layout (floats)
    float* hs_aux = (float*)d_ws;                   // N*8
    float* hr_h   = hs_aux + (size_t)N * 8;         // R*64
    float* hr_aux = hr_h + (size_t)R * 64;          // R*8
    float* preq   = hr_aux + (size_t)R * 8;         // B*8

    hipMemsetAsync(d_out, 0, (size_t)out_size * sizeof(float), stream);

    int waves_small = R + B;
    int blocks_small = (waves_small * 64 + 255) / 256;
    prep_small_kernel<<<blocks_small, 256, 0, stream>>>(
        q_rel, query_embed, Wqr_w, Wqr_b, rela_embed, Wr,
        hr_h, hr_aux, preq, R, B, A);

    int blocks_node = (N + 3) / 4;   // 4 waves/block
    prep_node_kernel<<<blocks_node, 256, 0, stream>>>(hidden, Ws, hs_aux, N, A);

    int blocks_edge = (E + 3) / 4;   // 4 waves/block
    edge_kernel<<<blocks_edge, 256, 0, stream>>>(
        edges, hidden, hr_h, hr_aux, hs_aux, preq,
        walpha_w, walpha_b, out, E, A);

    final_kernel<<<1024, 256, 0, stream>>>(out, Wh, N);
}

// Round 2
// 357.926 us; speedup vs baseline: 1.9180x; 1.9180x over previous
//
#include <hip/hip_runtime.h>
#include <hip/hip_bf16.h>

// Hyperbolic GNN layer. D = 64 = wavefront size: one wave per edge/node row.

__device__ __forceinline__ float wave_sum(float v) {
#pragma unroll
    for (int off = 32; off > 0; off >>= 1) v += __shfl_xor(v, off, 64);
    return v;
}

// ---- fast HW math (gfx950: v_rcp/v_sqrt/v_log/v_exp) ----
__device__ __forceinline__ float frcp(float x) {
#if __has_builtin(__builtin_amdgcn_rcpf)
    return __builtin_amdgcn_rcpf(x);
#else
    return 1.f / x;
#endif
}
__device__ __forceinline__ float fsqrt_(float x) {
#if __has_builtin(__builtin_amdgcn_sqrtf)
    return __builtin_amdgcn_sqrtf(x);
#else
    return sqrtf(x);
#endif
}
__device__ __forceinline__ float flog2_(float x) {
#if __has_builtin(__builtin_amdgcn_logf)
    return __builtin_amdgcn_logf(x);
#else
    return log2f(x);
#endif
}
__device__ __forceinline__ float fexp2_(float x) {
#if __has_builtin(__builtin_amdgcn_exp2f)
    return __builtin_amdgcn_exp2f(x);
#else
    return exp2f(x);
#endif
}

// expmap0 of u is a scalar multiple of u:
//   s = tanh(min(un,15))/un * min(1, maxn/||gamma||)
__device__ __forceinline__ void expmap0_scale(float norm, float& s, float& x2) {
    const float maxn = 1.0f - 0.004f;
    float un = fmaxf(norm, 1e-15f);
    float th = tanhf(fminf(un, 15.0f));
    float gs = th / un;
    float ng = gs * norm;
    float ps = ng > maxn ? maxn / ng : 1.0f;
    s = gs * ps;
    float sn = s * norm;
    x2 = sn * sn;
}

struct Aux8 { float v[8]; };

// --- prep for rel tables (R waves) and query rows (B waves) ---
__global__ void prep_small_kernel(const int* __restrict__ q_rel,
                                  const float* __restrict__ query_embed,
                                  const float* __restrict__ Wqr_w,
                                  const float* __restrict__ Wqr_b,
                                  const float* __restrict__ rela_embed,
                                  const float* __restrict__ Wr,
                                  float* __restrict__ hr_h,    // [R][64]
                                  float* __restrict__ hr_aux,  // [R][8]: 0..A-1, 6 = y2
                                  float* __restrict__ preq,    // [B][8]
                                  int R, int B, int A) {
    int w = (blockIdx.x * blockDim.x + threadIdx.x) >> 6;
    int lane = threadIdx.x & 63;
    if (w < R) {
        int r = w;
        float u = rela_embed[r * 64 + lane];
        float n2 = wave_sum(u * u);
        float s, y2;
        expmap0_scale(fsqrt_(n2), s, y2);
        hr_h[r * 64 + lane] = s * u;
        for (int a = 0; a < A; ++a) {
            float p = wave_sum(u * Wr[a * 64 + lane]);
            if (lane == 0) hr_aux[r * 8 + a] = p;
        }
        if (lane == 0) hr_aux[r * 8 + 6] = y2;
    } else if (w < R + B) {
        int b = w - R;
        int qr = q_rel[b];
        float q = query_embed[qr * 64 + lane];
        for (int a = 0; a < A; ++a) {
            float p = wave_sum(q * Wqr_w[a * 64 + lane]);
            if (lane == 0) preq[b * 8 + a] = p + Wqr_b[a];
        }
    }
}

// --- per-node tables: hsw[A], x2, scale (N waves) ---
__global__ void prep_node_kernel(const float* __restrict__ hidden,
                                 const float* __restrict__ Ws,
                                 float* __restrict__ hs_aux,  // [N][8]: 0..A-1, 6 = x2, 7 = s
                                 int N, int A) {
    int w = (blockIdx.x * blockDim.x + threadIdx.x) >> 6;
    if (w >= N) return;
    int lane = threadIdx.x & 63;
    float u = hidden[(long)w * 64 + lane];
    float n2 = wave_sum(u * u);
    float s, x2;
    expmap0_scale(fsqrt_(n2), s, x2);
    for (int a = 0; a < A; ++a) {
        float p = wave_sum(u * Ws[a * 64 + lane]);
        if (lane == 0) hs_aux[w * 8 + a] = p;
    }
    if (lane == 0) {
        hs_aux[w * 8 + 6] = x2;
        hs_aux[w * 8 + 7] = s;
    }
}

// --- per-edge body (A == 5 fast path) ---
__device__ __forceinline__ void do_edge(int e, int lane,
                                        const int* __restrict__ edges,
                                        const float* __restrict__ hidden,
                                        const float* __restrict__ hr_h,
                                        const Aux8* __restrict__ hr_aux8,
                                        const Aux8* __restrict__ hs_aux8,
                                        const Aux8* __restrict__ preq8,
                                        const float* wa, float wb,
                                        float* __restrict__ agg) {
    const int* er = edges + (size_t)e * 6;
    int r_idx = er[0];
    int rel   = er[2];
    int sub   = er[4];
    int obj   = er[5];

    Aux8 hs = hs_aux8[sub];
    Aux8 hr = hr_aux8[rel];
    Aux8 pq = preq8[r_idx];

    float s  = hs.v[7];
    float x2 = hs.v[6];
    float y2 = hr.v[6];

    float h = hidden[(size_t)sub * 64 + lane];
    float y = hr_h[(size_t)rel * 64 + lane];
    float x = h * s;

    float xy = wave_sum(x * y);

    // alpha = sigmoid(relu(pre) . walpha_w + walpha_b)
    float z = wb;
#pragma unroll
    for (int a = 0; a < 5; ++a)
        z += fmaxf(hs.v[a] + hr.v[a] + pq.v[a], 0.f) * wa[a];
    float alpha = frcp(1.f + fexp2_(-z * 1.44269504f));

    // mobius_add (c=1), analytic norm
    float Af  = 1.f + 2.f * xy + y2;
    float Bf  = 1.f - x2;
    float den = fmaxf(1.f + 2.f * xy + x2 * y2, 1e-15f);
    float inv = frcp(den);
    float nm2 = fmaxf(Af * Af * x2 + 2.f * Af * Bf * xy + Bf * Bf * y2, 0.f);
    float nm  = fsqrt_(nm2) * inv;

    // project (maxn = 0.996 < 1-1e-5, so artanh clip is subsumed)
    const float maxn = 1.0f - 0.004f;
    float ps  = nm > maxn ? maxn * frcp(nm) : 1.f;
    float nmp = fminf(nm, maxn);
    float yn  = fmaxf(nmp, 1e-15f);

    // artanh(yn) = 0.5*ln((1+yn)/(1-yn))
    float ratio = (1.f + yn) * frcp(1.f - yn);
    float art   = 0.34657359f * flog2_(ratio);   // 0.5*ln2 * log2

    float k  = inv * ps * alpha * art * frcp(yn);
    float cx = k * Af * s;
    float cy = k * Bf;
    float msg = fmaf(cx, h, cy * y);

    unsafeAtomicAdd(agg + (size_t)obj * 64 + lane, msg);
}

__global__ void edge_kernel(const int* __restrict__ edges,
                            const float* __restrict__ hidden,
                            const float* __restrict__ hr_h,
                            const float* __restrict__ hr_aux,
                            const float* __restrict__ hs_aux,
                            const float* __restrict__ preq,
                            const float* __restrict__ walpha_w,
                            const float* __restrict__ walpha_b,
                            float* __restrict__ agg,
                            int E) {
    int w = (blockIdx.x * blockDim.x + threadIdx.x) >> 6;
    w = __builtin_amdgcn_readfirstlane(w);
    int lane = threadIdx.x & 63;

    float wa[5];
#pragma unroll
    for (int a = 0; a < 5; ++a) wa[a] = walpha_w[a];
    float wb = walpha_b[0];

    const Aux8* hs8 = (const Aux8*)hs_aux;
    const Aux8* hr8 = (const Aux8*)hr_aux;
    const Aux8* pq8 = (const Aux8*)preq;

    int e0 = w * 2;
    int e1 = e0 + 1;
    if (e0 < E) do_edge(e0, lane, edges, hidden, hr_h, hr8, hs8, pq8, wa, wb, agg);
    if (e1 < E) do_edge(e1, lane, edges, hidden, hr_h, hr8, hs8, pq8, wa, wb, agg);
}

// --- generic-A fallback (correctness safety; A != 5 never expected) ---
__global__ void edge_kernel_generic(const int* __restrict__ edges,
                                    const float* __restrict__ hidden,
                                    const float* __restrict__ hr_h,
                                    const float* __restrict__ hr_aux,
                                    const float* __restrict__ hs_aux,
                                    const float* __restrict__ preq,
                                    const float* __restrict__ walpha_w,
                                    const float* __restrict__ walpha_b,
                                    float* __restrict__ agg,
                                    int E, int A) {
    int w = (blockIdx.x * blockDim.x + threadIdx.x) >> 6;
    if (w >= E) return;
    int lane = threadIdx.x & 63;
    const int* er = edges + (long)w * 6;
    int r_idx = er[0], rel = er[2], sub = er[4], obj = er[5];

    float s  = hs_aux[(long)sub * 8 + 7];
    float x2 = hs_aux[(long)sub * 8 + 6];
    float h  = hidden[(long)sub * 64 + lane];
    float x  = h * s;
    float y  = hr_h[(long)rel * 64 + lane];
    float y2 = hr_aux[(long)rel * 8 + 6];
    float xy = wave_sum(x * y);

    float z = walpha_b[0];
    for (int a = 0; a < A; ++a) {
        float pre = hs_aux[(long)sub * 8 + a] + hr_aux[(long)rel * 8 + a] + preq[(long)r_idx * 8 + a];
        z += fmaxf(pre, 0.f) * walpha_w[a];
    }
    float alpha = frcp(1.f + fexp2_(-z * 1.44269504f));

    float Af = 1.f + 2.f * xy + y2;
    float Bf = 1.f - x2;
    float den = fmaxf(1.f + 2.f * xy + x2 * y2, 1e-15f);
    float inv = frcp(den);
    float nm2 = fmaxf(Af * Af * x2 + 2.f * Af * Bf * xy + Bf * Bf * y2, 0.f);
    float nm = fsqrt_(nm2) * inv;
    const float maxn = 1.0f - 0.004f;
    float ps = nm > maxn ? maxn * frcp(nm) : 1.f;
    float nmp = fminf(nm, maxn);
    float yn = fmaxf(nmp, 1e-15f);
    float ratio = (1.f + yn) * frcp(1.f - yn);
    float art = 0.34657359f * flog2_(ratio);
    float k = inv * ps * alpha * art * frcp(yn);
    float msg = fmaf(k * Af * s, h, k * Bf * y);
    unsafeAtomicAdd(agg + (long)obj * 64 + lane, msg);
}

// --- final: a = agg @ Wh^T (in-place per row), then p_exp_map + logmap0 ---
__global__ void final_kernel(float* __restrict__ out,
                             const float* __restrict__ Wh,
                             int N) {
    __shared__ float WhT[64 * 64];   // WhT[k][d] = Wh[d][k]
    int t = threadIdx.x;
    for (int i = t; i < 64 * 64; i += blockDim.x) {
        int row = i >> 6, col = i & 63;
        WhT[col * 64 + row] = Wh[i];
    }
    __syncthreads();

    int lane = t & 63;
    int wl = t >> 6;
    int wpb = blockDim.x >> 6;
    int wg = blockIdx.x * wpb + wl;
    int wstride = gridDim.x * wpb;

    for (int n = wg; n < N; n += wstride) {
        float v = out[(long)n * 64 + lane];
        float a = 0.f;
#pragma unroll
        for (int k = 0; k < 64; ++k)
            a = fmaf(__shfl(v, k, 64), WhT[k * 64 + lane], a);

        float n2 = wave_sum(a * a);
        float na = fsqrt_(n2);
        float nv = fmaxf(na, 1e-10f);
        float pn = tanhf(nv);
        float rinv = frcp(nv);
        float p = pn * a * rinv;                 // p_exp_map
        float np = pn * (na * rinv);             // ||p||
        float yn = fmaxf(np, 1e-15f);
        float tt = fminf(yn, 1.f - 1e-5f);
        float ratio = (1.f + tt) * frcp(1.f - tt);
        float art = 0.34657359f * flog2_(ratio);
        out[(long)n * 64 + lane] = p * art * frcp(yn);
    }
}

extern "C" void kernel_launch(void* const* d_in, const int* in_sizes, int n_in,
                              void* d_out, int out_size, void* d_ws, size_t ws_size,
                              hipStream_t stream) {
    const int*   q_rel       = (const int*)d_in[1];
    const float* hidden      = (const float*)d_in[2];
    const int*   edges       = (const int*)d_in[3];
    const float* rela_embed  = (const float*)d_in[6];
    const float* query_embed = (const float*)d_in[7];
    const float* Ws          = (const float*)d_in[8];
    const float* Wr          = (const float*)d_in[9];
    const float* Wqr_w       = (const float*)d_in[10];
    const float* Wqr_b       = (const float*)d_in[11];
    const float* walpha_w    = (const float*)d_in[12];
    const float* walpha_b    = (const float*)d_in[13];
    const float* Wh          = (const float*)d_in[14];

    const int D = 64;
    int B = in_sizes[0];
    int E = in_sizes[3] / 6;
    int A = in_sizes[11];
    int R = in_sizes[6] / D;
    int N = out_size / D;

    float* out = (float*)d_out;

    float* hs_aux = (float*)d_ws;                   // N*8
    float* hr_h   = hs_aux + (size_t)N * 8;         // R*64
    float* hr_aux = hr_h + (size_t)R * 64;          // R*8
    float* preq   = hr_aux + (size_t)R * 8;         // B*8

    hipMemsetAsync(d_out, 0, (size_t)out_size * sizeof(float), stream);

    int waves_small = R + B;
    int blocks_small = (waves_small * 64 + 255) / 256;
    prep_small_kernel<<<blocks_small, 256, 0, stream>>>(
        q_rel, query_embed, Wqr_w, Wqr_b, rela_embed, Wr,
        hr_h, hr_aux, preq, R, B, A);

    int blocks_node = (N + 3) / 4;
    prep_node_kernel<<<blocks_node, 256, 0, stream>>>(hidden, Ws, hs_aux, N, A);

    if (A == 5) {
        int waves = (E + 1) / 2;
        int blocks_edge = (waves + 3) / 4;
        edge_kernel<<<blocks_edge, 256, 0, stream>>>(
            edges, hidden, hr_h, hr_aux, hs_aux, preq,
            walpha_w, walpha_b, out, E);
    } else {
        int blocks_edge = (E + 3) / 4;
        edge_kernel_generic<<<blocks_edge, 256, 0, stream>>>(
            edges, hidden, hr_h, hr_aux, hs_aux, preq,
            walpha_w, walpha_b, out, E, A);
    }

    final_kernel<<<1024, 256, 0, stream>>>(out, Wh, N);
}

// Round 3
// 345.957 us; speedup vs baseline: 1.9843x; 1.0346x over previous
//
#include <hip/hip_runtime.h>
#include <hip/hip_bf16.h>
#include <hip/hip_fp16.h>

// Hyperbolic GNN layer. D = 64. Edge kernel: quarter-wave (16 lanes x float4)
// per edge, f16 packed atomics for the segment sum.

__device__ __forceinline__ float wave_sum(float v) {
#pragma unroll
    for (int off = 32; off > 0; off >>= 1) v += __shfl_xor(v, off, 64);
    return v;
}

// ---- fast HW math ----
__device__ __forceinline__ float frcp(float x) {
#if __has_builtin(__builtin_amdgcn_rcpf)
    return __builtin_amdgcn_rcpf(x);
#else
    return 1.f / x;
#endif
}
__device__ __forceinline__ float fsqrt_(float x) {
#if __has_builtin(__builtin_amdgcn_sqrtf)
    return __builtin_amdgcn_sqrtf(x);
#else
    return sqrtf(x);
#endif
}
__device__ __forceinline__ float flog2_(float x) {
#if __has_builtin(__builtin_amdgcn_logf)
    return __builtin_amdgcn_logf(x);
#else
    return log2f(x);
#endif
}
__device__ __forceinline__ float fexp2_(float x) {
#if __has_builtin(__builtin_amdgcn_exp2f)
    return __builtin_amdgcn_exp2f(x);
#else
    return exp2f(x);
#endif
}

// expmap0 scale: s such that expmap0(u) = s*u; x2 = ||s*u||^2
__device__ __forceinline__ void expmap0_scale(float norm, float& s, float& x2) {
    const float maxn = 1.0f - 0.004f;
    float un = fmaxf(norm, 1e-15f);
    float th = tanhf(fminf(un, 15.0f));
    float gs = th / un;
    float ng = gs * norm;
    float ps = ng > maxn ? maxn / ng : 1.0f;
    s = gs * ps;
    float sn = s * norm;
    x2 = sn * sn;
}

// --- prep: rel tables (R waves) and query rows (B waves) ---
__global__ void prep_small_kernel(const int* __restrict__ q_rel,
                                  const float* __restrict__ query_embed,
                                  const float* __restrict__ Wqr_w,
                                  const float* __restrict__ Wqr_b,
                                  const float* __restrict__ rela_embed,
                                  const float* __restrict__ Wr,
                                  float* __restrict__ hr_h,    // [R][64]
                                  float* __restrict__ hr_aux,  // [R][8]: 0..A-1, 6=y2
                                  float* __restrict__ preq,    // [B][8]
                                  int R, int B, int A) {
    int w = (blockIdx.x * blockDim.x + threadIdx.x) >> 6;
    int lane = threadIdx.x & 63;
    if (w < R) {
        int r = w;
        float u = rela_embed[r * 64 + lane];
        float n2 = wave_sum(u * u);
        float s, y2;
        expmap0_scale(fsqrt_(n2), s, y2);
        hr_h[r * 64 + lane] = s * u;
        for (int a = 0; a < A; ++a) {
            float p = wave_sum(u * Wr[a * 64 + lane]);
            if (lane == 0) hr_aux[r * 8 + a] = p;
        }
        if (lane == 0) hr_aux[r * 8 + 6] = y2;
    } else if (w < R + B) {
        int b = w - R;
        int qr = q_rel[b];
        float q = query_embed[qr * 64 + lane];
        for (int a = 0; a < A; ++a) {
            float p = wave_sum(q * Wqr_w[a * 64 + lane]);
            if (lane == 0) preq[b * 8 + a] = p + Wqr_b[a];
        }
    }
}

// --- per-node tables, A==5 fast path, interleaved butterflies ---
__global__ void prep_node_kernel5(const float* __restrict__ hidden,
                                  const float* __restrict__ Ws,
                                  float* __restrict__ hs_aux,  // [N][8]
                                  int N) {
    int w = (blockIdx.x * blockDim.x + threadIdx.x) >> 6;
    if (w >= N) return;
    int lane = threadIdx.x & 63;
    float u = hidden[(size_t)w * 64 + lane];
    float p0 = u * u;
    float p1 = u * Ws[0 * 64 + lane];
    float p2 = u * Ws[1 * 64 + lane];
    float p3 = u * Ws[2 * 64 + lane];
    float p4 = u * Ws[3 * 64 + lane];
    float p5 = u * Ws[4 * 64 + lane];
#pragma unroll
    for (int off = 1; off < 64; off <<= 1) {
        p0 += __shfl_xor(p0, off, 64);
        p1 += __shfl_xor(p1, off, 64);
        p2 += __shfl_xor(p2, off, 64);
        p3 += __shfl_xor(p3, off, 64);
        p4 += __shfl_xor(p4, off, 64);
        p5 += __shfl_xor(p5, off, 64);
    }
    float s, x2;
    expmap0_scale(fsqrt_(p0), s, x2);
    if (lane == 0) {
        float4* o = (float4*)(hs_aux + (size_t)w * 8);
        o[0] = make_float4(p1, p2, p3, p4);
        o[1] = make_float4(p5, 0.f, x2, s);
    }
}

// generic-A fallback
__global__ void prep_node_kernel(const float* __restrict__ hidden,
                                 const float* __restrict__ Ws,
                                 float* __restrict__ hs_aux, int N, int A) {
    int w = (blockIdx.x * blockDim.x + threadIdx.x) >> 6;
    if (w >= N) return;
    int lane = threadIdx.x & 63;
    float u = hidden[(size_t)w * 64 + lane];
    float n2 = wave_sum(u * u);
    float s, x2;
    expmap0_scale(fsqrt_(n2), s, x2);
    for (int a = 0; a < A; ++a) {
        float p = wave_sum(u * Ws[a * 64 + lane]);
        if (lane == 0) hs_aux[w * 8 + a] = p;
    }
    if (lane == 0) { hs_aux[w * 8 + 6] = x2; hs_aux[w * 8 + 7] = s; }
}

// --- main edge kernel: quarter-wave per edge, f16 pk atomics ---
__global__ __launch_bounds__(256) void edge_kernel4(
    const int* __restrict__ edges,
    const float* __restrict__ hidden,
    const float* __restrict__ hr_h,
    const float* __restrict__ hr_aux,
    const float* __restrict__ hs_aux,
    const float* __restrict__ preq,
    const float* __restrict__ walpha_w,
    const float* __restrict__ walpha_b,
    __half2* __restrict__ agg,
    int E)
{
    int wid = (blockIdx.x * blockDim.x + threadIdx.x) >> 6;
    int lane = threadIdx.x & 63;
    int q = lane >> 4;      // which edge of the 4
    int j = lane & 15;      // float4 index within row

    int e = wid * 4 + q;
    bool act = e < E;
    int ec = act ? e : E - 1;

    const int* er = edges + (size_t)ec * 6;
    int r_idx = (*(const int2*)(er)).x;
    int rel   = (*(const int2*)(er + 2)).x;
    int2 so   = *(const int2*)(er + 4);
    int sub = so.x, obj = so.y;

    const float4* hsA = (const float4*)(hs_aux + (size_t)sub * 8);
    float4 hs0 = hsA[0], hs1 = hsA[1];
    const float4* hrA = (const float4*)(hr_aux + (size_t)rel * 8);
    float4 hr0 = hrA[0], hr1 = hrA[1];
    const float4* pqA = (const float4*)(preq + (size_t)r_idx * 8);
    float4 pq0 = pqA[0], pq1 = pqA[1];

    float s  = hs1.w;
    float x2 = hs1.z;
    float y2 = hr1.z;

    float4 h = *(const float4*)(hidden + (size_t)sub * 64 + 4 * j);
    float4 y = *(const float4*)(hr_h + (size_t)rel * 64 + 4 * j);

    float p = h.x * y.x;
    p = fmaf(h.y, y.y, p);
    p = fmaf(h.z, y.z, p);
    p = fmaf(h.w, y.w, p);
#pragma unroll
    for (int off = 1; off < 16; off <<= 1) p += __shfl_xor(p, off, 64);
    float xy = p * s;

    float4 w4 = *(const float4*)walpha_w;
    float w4e = walpha_w[4];
    float z = walpha_b[0];
    z = fmaf(fmaxf(hs0.x + hr0.x + pq0.x, 0.f), w4.x, z);
    z = fmaf(fmaxf(hs0.y + hr0.y + pq0.y, 0.f), w4.y, z);
    z = fmaf(fmaxf(hs0.z + hr0.z + pq0.z, 0.f), w4.z, z);
    z = fmaf(fmaxf(hs0.w + hr0.w + pq0.w, 0.f), w4.w, z);
    z = fmaf(fmaxf(hs1.x + hr1.x + pq1.x, 0.f), w4e, z);
    float alpha = frcp(1.f + fexp2_(z * -1.44269504f));

    float Af  = 1.f + 2.f * xy + y2;
    float Bf  = 1.f - x2;
    float den = fmaxf(1.f + 2.f * xy + x2 * y2, 1e-15f);
    float inv = frcp(den);
    float nm2 = fmaxf(fmaf(Af * Af, x2, fmaf(2.f * Af * Bf, xy, Bf * Bf * y2)), 0.f);
    float nm  = fsqrt_(nm2) * inv;
    const float maxn = 1.0f - 0.004f;
    float ps  = nm > maxn ? maxn * frcp(nm) : 1.f;
    float yn  = fmaxf(fminf(nm, maxn), 1e-15f);
    float ratio = (1.f + yn) * frcp(1.f - yn);
    float art = 0.34657359f * flog2_(ratio);     // artanh
    float k  = inv * ps * alpha * art * frcp(yn);
    float cx = k * Af * s;
    float cy = k * Bf;

    float m0 = fmaf(cx, h.x, cy * y.x);
    float m1 = fmaf(cx, h.y, cy * y.y);
    float m2 = fmaf(cx, h.z, cy * y.z);
    float m3 = fmaf(cx, h.w, cy * y.w);
    __half2 pk0 = __floats2half2_rn(m0, m1);
    __half2 pk1 = __floats2half2_rn(m2, m3);
    if (act) {
        __half2* dst = agg + (size_t)obj * 32 + 2 * j;
        unsafeAtomicAdd(dst, pk0);
        unsafeAtomicAdd(dst + 1, pk1);
    }
}

// f32 fallback edge kernel (any A, agg f32 = d_out)
__global__ void edge_kernel_f32(const int* __restrict__ edges,
                                const float* __restrict__ hidden,
                                const float* __restrict__ hr_h,
                                const float* __restrict__ hr_aux,
                                const float* __restrict__ hs_aux,
                                const float* __restrict__ preq,
                                const float* __restrict__ walpha_w,
                                const float* __restrict__ walpha_b,
                                float* __restrict__ agg,
                                int E, int A) {
    int w = (blockIdx.x * blockDim.x + threadIdx.x) >> 6;
    if (w >= E) return;
    int lane = threadIdx.x & 63;
    const int* er = edges + (size_t)w * 6;
    int r_idx = er[0], rel = er[2], sub = er[4], obj = er[5];

    float s  = hs_aux[(size_t)sub * 8 + 7];
    float x2 = hs_aux[(size_t)sub * 8 + 6];
    float h  = hidden[(size_t)sub * 64 + lane];
    float x  = h * s;
    float y  = hr_h[(size_t)rel * 64 + lane];
    float y2 = hr_aux[(size_t)rel * 8 + 6];
    float xy = wave_sum(x * y);

    float z = walpha_b[0];
    for (int a = 0; a < A; ++a) {
        float pre = hs_aux[(size_t)sub * 8 + a] + hr_aux[(size_t)rel * 8 + a] + preq[(size_t)r_idx * 8 + a];
        z += fmaxf(pre, 0.f) * walpha_w[a];
    }
    float alpha = frcp(1.f + fexp2_(z * -1.44269504f));

    float Af = 1.f + 2.f * xy + y2;
    float Bf = 1.f - x2;
    float den = fmaxf(1.f + 2.f * xy + x2 * y2, 1e-15f);
    float inv = frcp(den);
    float nm2 = fmaxf(Af * Af * x2 + 2.f * Af * Bf * xy + Bf * Bf * y2, 0.f);
    float nm = fsqrt_(nm2) * inv;
    const float maxn = 1.0f - 0.004f;
    float ps = nm > maxn ? maxn * frcp(nm) : 1.f;
    float yn = fmaxf(fminf(nm, maxn), 1e-15f);
    float ratio = (1.f + yn) * frcp(1.f - yn);
    float art = 0.34657359f * flog2_(ratio);
    float k = inv * ps * alpha * art * frcp(yn);
    float msg = fmaf(k * Af * s, h, k * Bf * y);
    unsafeAtomicAdd(agg + (size_t)obj * 64 + lane, msg);
}

// --- final: a = agg @ Wh^T, then p_exp_map + logmap0 ---
template <bool F16>
__global__ void final_kernel_t(float* __restrict__ out,
                               const __half* __restrict__ agg16,
                               const float* __restrict__ Wh,
                               int N) {
    __shared__ float WhT[64 * 64];   // WhT[k][d] = Wh[d][k]
    int t = threadIdx.x;
    for (int i = t; i < 64 * 64; i += blockDim.x) {
        int row = i >> 6, col = i & 63;
        WhT[col * 64 + row] = Wh[i];
    }
    __syncthreads();

    int lane = t & 63;
    int wl = t >> 6;
    int wpb = blockDim.x >> 6;
    int wg = blockIdx.x * wpb + wl;
    int wstride = gridDim.x * wpb;

    for (int n = wg; n < N; n += wstride) {
        float v;
        if (F16) v = __half2float(agg16[(size_t)n * 64 + lane]);
        else     v = out[(size_t)n * 64 + lane];
        float a = 0.f;
#pragma unroll
        for (int k = 0; k < 64; ++k)
            a = fmaf(__shfl(v, k, 64), WhT[k * 64 + lane], a);

        float n2 = wave_sum(a * a);
        float na = fsqrt_(n2);
        float nv = fmaxf(na, 1e-10f);
        float pn = tanhf(nv);
        float rinv = frcp(nv);
        float pp = pn * a * rinv;                // p_exp_map
        float np = pn * (na * rinv);             // ||p||
        float yn = fmaxf(np, 1e-15f);
        float tt = fminf(yn, 1.f - 1e-5f);
        float ratio = (1.f + tt) * frcp(1.f - tt);
        float art = 0.34657359f * flog2_(ratio);
        out[(size_t)n * 64 + lane] = pp * art * frcp(yn);
    }
}

extern "C" void kernel_launch(void* const* d_in, const int* in_sizes, int n_in,
                              void* d_out, int out_size, void* d_ws, size_t ws_size,
                              hipStream_t stream) {
    const int*   q_rel       = (const int*)d_in[1];
    const float* hidden      = (const float*)d_in[2];
    const int*   edges       = (const int*)d_in[3];
    const float* rela_embed  = (const float*)d_in[6];
    const float* query_embed = (const float*)d_in[7];
    const float* Ws          = (const float*)d_in[8];
    const float* Wr          = (const float*)d_in[9];
    const float* Wqr_w       = (const float*)d_in[10];
    const float* Wqr_b       = (const float*)d_in[11];
    const float* walpha_w    = (const float*)d_in[12];
    const float* walpha_b    = (const float*)d_in[13];
    const float* Wh          = (const float*)d_in[14];

    const int D = 64;
    int B = in_sizes[0];
    int E = in_sizes[3] / 6;
    int A = in_sizes[11];
    int R = in_sizes[6] / D;
    int N = out_size / D;

    float* out = (float*)d_out;

    // f16 path workspace: agg16 [N][64] halfs, then f32 tables
    size_t agg_bytes = (size_t)N * 64 * sizeof(__half);
    size_t tab_floats = (size_t)N * 8 + (size_t)R * 64 + (size_t)R * 8 + (size_t)B * 8;
    size_t need = agg_bytes + tab_floats * sizeof(float);
    bool f16path = (A == 5) && (ws_size >= need);

    if (f16path) {
        __half2* agg16 = (__half2*)d_ws;
        float* hs_aux = (float*)((char*)d_ws + agg_bytes);   // N*8
        float* hr_h   = hs_aux + (size_t)N * 8;              // R*64
        float* hr_aux = hr_h + (size_t)R * 64;               // R*8
        float* preq   = hr_aux + (size_t)R * 8;              // B*8

        hipMemsetAsync(d_ws, 0, agg_bytes, stream);

        int waves_small = R + B;
        prep_small_kernel<<<(waves_small * 64 + 255) / 256, 256, 0, stream>>>(
            q_rel, query_embed, Wqr_w, Wqr_b, rela_embed, Wr,
            hr_h, hr_aux, preq, R, B, A);

        prep_node_kernel5<<<(N + 3) / 4, 256, 0, stream>>>(hidden, Ws, hs_aux, N);

        int waves = (E + 3) / 4;
        int blocks_edge = (waves + 3) / 4;
        edge_kernel4<<<blocks_edge, 256, 0, stream>>>(
            edges, hidden, hr_h, hr_aux, hs_aux, preq,
            walpha_w, walpha_b, agg16, E);

        final_kernel_t<true><<<1024, 256, 0, stream>>>(out, (const __half*)agg16, Wh, N);
    } else {
        float* hs_aux = (float*)d_ws;
        float* hr_h   = hs_aux + (size_t)N * 8;
        float* hr_aux = hr_h + (size_t)R * 64;
        float* preq   = hr_aux + (size_t)R * 8;

        hipMemsetAsync(d_out, 0, (size_t)out_size * sizeof(float), stream);

        int waves_small = R + B;
        prep_small_kernel<<<(waves_small * 64 + 255) / 256, 256, 0, stream>>>(
            q_rel, query_embed, Wqr_w, Wqr_b, rela_embed, Wr,
            hr_h, hr_aux, preq, R, B, A);

        prep_node_kernel<<<(N + 3) / 4, 256, 0, stream>>>(hidden, Ws, hs_aux, N, A);

        edge_kernel_f32<<<(E + 3) / 4, 256, 0, stream>>>(
            edges, hidden, hr_h, hr_aux, hs_aux, preq,
            walpha_w, walpha_b, out, E, A);

        final_kernel_t<false><<<1024, 256, 0, stream>>>(out, nullptr, Wh, N);
    }
}